// Round 3
// baseline (983.675 us; speedup 1.0000x reference)
//
#include <hip/hip_runtime.h>

#define DIM 100
#define BHALF 50   // rows of T per transform block

// Fallback storage if ws_size is too small:
__device__ float2 g_U[DIM * DIM];
__device__ float2 g_UH[DIM * DIM];

// ---------------------------------------------------------------------------
// Kernel 1: build U = D * T_K ... T_1.
// Givens steps touch ROWS only, so columns evolve independently: 2 blocks,
// each owns a 50-column slice (LDS 100x50 float2 = 40,000 B). Within a layer
// the <=50 (m,m+1) pairs are row-disjoint -> fully parallel.
//   pU[i*DIM+j]  = U[i][j] (after diagonal phase)
//   pUH[l*DIM+j] = conj(U[j][l])
// ---------------------------------------------------------------------------
__global__ __launch_bounds__(512) void build_U_kernel(
    const float* __restrict__ theta, const float* __restrict__ phi,
    const float* __restrict__ dphase, float2* pU, float2* pUH) {
  float2* __restrict__ outU = pU ? pU : g_U;
  float2* __restrict__ outUH = pUH ? pUH : g_UH;
  __shared__ float2 U[DIM][BHALF];
  __shared__ float4 trig[50];  // cos(th), sin(th), cos(ph), sin(ph)
  const int t = threadIdx.x;
  const int c0 = blockIdx.x * BHALF;  // global column offset of this slice

  for (int idx = t; idx < DIM * BHALF; idx += 512) {
    int i = idx / BHALF, c = idx - i * BHALF;
    U[i][c] = make_float2((i == c0 + c) ? 1.0f : 0.0f, 0.0f);
  }
  __syncthreads();

  for (int layer = 0; layer < DIM; ++layer) {
    const int start = layer & 1;
    const int npairs = 50 - start;
    const int base = (layer >> 1) * 99 + start * 50;
    if (t < npairs) {
      float th = theta[base + t];
      float ph = phi[base + t];
      trig[t] = make_float4(cosf(th), sinf(th), cosf(ph), sinf(ph));
    }
    __syncthreads();
    for (int w = t; w < npairs * BHALF; w += 512) {
      const int p = w / BHALF;
      const int c = w - p * BHALF;
      const int m = start + 2 * p;
      const int n = m + 1;
      const float4 tg = trig[p];
      const float cth = tg.x, sth = tg.y, cp = tg.z, sp = tg.w;
      const float2 rm = U[m][c];
      const float2 rn = U[n][c];
      const float ar = cp * rm.x - sp * rm.y;  // (e^{i ph} * rm).re
      const float ai = cp * rm.y + sp * rm.x;  // (e^{i ph} * rm).im
      U[m][c] = make_float2(cth * ar - sth * rn.x, cth * ai - sth * rn.y);
      U[n][c] = make_float2(sth * ar + cth * rn.x, sth * ai + cth * rn.y);
    }
    __syncthreads();
  }

  for (int idx = t; idx < DIM * BHALF; idx += 512) {
    int i = idx / BHALF, c = idx - i * BHALF;
    int j = c0 + c;
    float d = dphase[i];
    float cd = cosf(d), sd = sinf(d);
    float2 u = U[i][c];
    float2 v = make_float2(cd * u.x - sd * u.y, cd * u.y + sd * u.x);
    outU[i * DIM + j] = v;
    outUH[j * DIM + i] = make_float2(v.x, -v.y);
  }
}

// ---------------------------------------------------------------------------
// Kernel 2: fused  out[b, i0:i0+50, :] = (U[i0:i0+50,:] @ X[b]) @ U^H
// One block per (batch, half). T (50x100 complex) in LDS (40 KB). 250 active
// threads; 5x4 complex register tile. gi = t/25 (5-row group), gl = t%25
// (4-col group): consecutive t -> consecutive columns (coalesced float4
// loads); the 25 lanes of a gi-group broadcast-read the same U/T element.
// Epilogue layout chosen at runtime from out_size; every store is guarded.
// ---------------------------------------------------------------------------
__global__ __launch_bounds__(256) void transform_kernel(
    const float* __restrict__ xre, const float* __restrict__ xim,
    const float2* pU, const float2* pUH, float* __restrict__ out,
    int out_size) {
  __shared__ float2 T[BHALF][DIM];
  const int b = blockIdx.x >> 1;
  const int i0 = (blockIdx.x & 1) * BHALF;
  const int t = threadIdx.x;
  const int gi = t / 25;
  const int gl = t - gi * 25;
  const bool active = (t < 250);

  const float2* __restrict__ U = pU ? pU : g_U;
  const float* __restrict__ UHf = (const float*)(pUH ? pUH : g_UH);
  const float* __restrict__ Xre = xre + (size_t)b * DIM * DIM;
  const float* __restrict__ Xim = xim + (size_t)b * DIM * DIM;

  float2 acc[5][4];

  // ---- stage 1: T = U[i0:i0+50, :] @ X[b] ----
  if (active) {
#pragma unroll
    for (int r = 0; r < 5; ++r)
#pragma unroll
      for (int c = 0; c < 4; ++c) acc[r][c] = make_float2(0.f, 0.f);
    const int ib = i0 + gi * 5;
    const int lb = gl * 4;
    for (int j = 0; j < DIM; ++j) {
      const float4 xr = *(const float4*)(Xre + j * DIM + lb);
      const float4 xi = *(const float4*)(Xim + j * DIM + lb);
#pragma unroll
      for (int r = 0; r < 5; ++r) {
        const float2 u = U[(ib + r) * DIM + j];
        acc[r][0].x += u.x * xr.x - u.y * xi.x;
        acc[r][0].y += u.x * xi.x + u.y * xr.x;
        acc[r][1].x += u.x * xr.y - u.y * xi.y;
        acc[r][1].y += u.x * xi.y + u.y * xr.y;
        acc[r][2].x += u.x * xr.z - u.y * xi.z;
        acc[r][2].y += u.x * xi.z + u.y * xr.z;
        acc[r][3].x += u.x * xr.w - u.y * xi.w;
        acc[r][3].y += u.x * xi.w + u.y * xr.w;
      }
    }
#pragma unroll
    for (int r = 0; r < 5; ++r)
#pragma unroll
      for (int c = 0; c < 4; ++c) T[gi * 5 + r][lb + c] = acc[r][c];
  }
  __syncthreads();

  // ---- stage 2: out rows = T @ U^H ----
  if (active) {
#pragma unroll
    for (int r = 0; r < 5; ++r)
#pragma unroll
      for (int c = 0; c < 4; ++c) acc[r][c] = make_float2(0.f, 0.f);
    const int jb = gl * 4;
    for (int l = 0; l < DIM; ++l) {
      float2 t5[5];
#pragma unroll
      for (int r = 0; r < 5; ++r) t5[r] = T[gi * 5 + r][l];
      const float4 uh01 = *(const float4*)(UHf + (l * DIM + jb) * 2);
      const float4 uh23 = *(const float4*)(UHf + (l * DIM + jb) * 2 + 4);
#pragma unroll
      for (int r = 0; r < 5; ++r) {
        acc[r][0].x += t5[r].x * uh01.x - t5[r].y * uh01.y;
        acc[r][0].y += t5[r].x * uh01.y + t5[r].y * uh01.x;
        acc[r][1].x += t5[r].x * uh01.z - t5[r].y * uh01.w;
        acc[r][1].y += t5[r].x * uh01.w + t5[r].y * uh01.z;
        acc[r][2].x += t5[r].x * uh23.x - t5[r].y * uh23.y;
        acc[r][2].y += t5[r].x * uh23.y + t5[r].y * uh23.x;
        acc[r][3].x += t5[r].x * uh23.z - t5[r].y * uh23.w;
        acc[r][3].y += t5[r].x * uh23.w + t5[r].y * uh23.z;
      }
    }

    const int B = (int)(gridDim.x >> 1);
    const size_t totalc = (size_t)B * DIM * DIM;  // complex element count
    const bool interleaved = ((size_t)out_size >= 2 * totalc);
    if (interleaved) {
      // complex64 viewed as interleaved float pairs, row-major [B,N,N]
      float* outp = out + ((size_t)b * DIM + i0) * DIM * 2;
#pragma unroll
      for (int r = 0; r < 5; ++r) {
        float* o = outp + (size_t)(gi * 5 + r) * DIM * 2 + jb * 2;
        size_t idx = (size_t)(o - out);
        if (idx + 8 <= (size_t)out_size) {
          *(float4*)(o) =
              make_float4(acc[r][0].x, acc[r][0].y, acc[r][1].x, acc[r][1].y);
          *(float4*)(o + 4) =
              make_float4(acc[r][2].x, acc[r][2].y, acc[r][3].x, acc[r][3].y);
        }
      }
    } else {
      // real part only, row-major [B,N,N]
#pragma unroll
      for (int r = 0; r < 5; ++r) {
        float* o = out + ((size_t)b * DIM + i0 + gi * 5 + r) * DIM + jb;
        size_t idx = (size_t)(o - out);
        if (idx + 4 <= (size_t)out_size) {
          *(float4*)(o) =
              make_float4(acc[r][0].x, acc[r][1].x, acc[r][2].x, acc[r][3].x);
        }
      }
    }
  }
}

extern "C" void kernel_launch(void* const* d_in, const int* in_sizes, int n_in,
                              void* d_out, int out_size, void* d_ws, size_t ws_size,
                              hipStream_t stream) {
  const float* xre = (const float*)d_in[0];
  const float* xim = (const float*)d_in[1];
  const float* theta = (const float*)d_in[2];
  const float* phi = (const float*)d_in[3];
  const float* dphase = (const float*)d_in[4];
  float* out = (float*)d_out;

  // U/U^H scratch: d_ws if big enough, else device globals (null sentinel).
  const size_t need = (size_t)2 * DIM * DIM * sizeof(float2);  // 160,000 B
  float2* pU = nullptr;
  float2* pUH = nullptr;
  if (d_ws != nullptr && ws_size >= need) {
    pU = (float2*)d_ws;
    pUH = pU + DIM * DIM;
  }

  hipLaunchKernelGGL(build_U_kernel, dim3(2), dim3(512), 0, stream,
                     theta, phi, dphase, pU, pUH);
  const int B = in_sizes[0] / (DIM * DIM);  // 2048
  hipLaunchKernelGGL(transform_kernel, dim3(B * 2), dim3(256), 0, stream,
                     xre, xim, pU, pUH, out, out_size);
}

// Round 4
// 450.513 us; speedup vs baseline: 2.1835x; 2.1835x over previous
//
#include <hip/hip_runtime.h>

#define DIM 100

typedef _Float16 half8 __attribute__((ext_vector_type(8)));
typedef _Float16 half4v __attribute__((ext_vector_type(4)));
typedef float floatx4 __attribute__((ext_vector_type(4)));

// Module-scope storage (rewritten every launch; no d_ws dependence):
__device__ float2 g_U[DIM * DIM];        // built unitary (after phase layer)
// MFMA fragment planes: [0]=Ur, [1]=Ui, [2]=-Ui. Tile (it,kt) covers U rows
// [it*16,it*16+16) x cols [kt*32,kt*32+32), zero-padded past 100.
// Element j of lane L in tile (it,kt) = plane[it*16+(L&15)][kt*32+(L>>4)*8+j].
// Serves BOTH stage-1 A-fragments and stage-2 B-fragments (identical layout).
__device__ half8 g_frag[3][7 * 4 * 64];

// ---------------------------------------------------------------------------
// Kernel 1: build U = D * T_K ... T_1 (Clements mesh scan).
// Columns evolve independently under row-pair Givens updates: 2 blocks, each
// owns 50 columns in LDS (100x50 float2 = 40 KB). Layer-parallel within each
// of the 100 layers.
// ---------------------------------------------------------------------------
__global__ __launch_bounds__(512) void build_U_kernel(
    const float* __restrict__ theta, const float* __restrict__ phi,
    const float* __restrict__ dphase) {
  __shared__ float2 U[DIM][50];
  __shared__ float4 trig[50];  // cos(th), sin(th), cos(ph), sin(ph)
  const int t = threadIdx.x;
  const int c0 = blockIdx.x * 50;

  for (int idx = t; idx < DIM * 50; idx += 512) {
    int i = idx / 50, c = idx - i * 50;
    U[i][c] = make_float2((i == c0 + c) ? 1.0f : 0.0f, 0.0f);
  }
  __syncthreads();

  for (int layer = 0; layer < DIM; ++layer) {
    const int start = layer & 1;
    const int npairs = 50 - start;
    const int base = (layer >> 1) * 99 + start * 50;
    if (t < npairs) {
      float th = theta[base + t];
      float ph = phi[base + t];
      trig[t] = make_float4(cosf(th), sinf(th), cosf(ph), sinf(ph));
    }
    __syncthreads();
    for (int w = t; w < npairs * 50; w += 512) {
      const int p = w / 50;
      const int c = w - p * 50;
      const int m = start + 2 * p;
      const int n = m + 1;
      const float4 tg = trig[p];
      const float cth = tg.x, sth = tg.y, cp = tg.z, sp = tg.w;
      const float2 rm = U[m][c];
      const float2 rn = U[n][c];
      const float ar = cp * rm.x - sp * rm.y;  // (e^{i ph} * rm).re
      const float ai = cp * rm.y + sp * rm.x;  // (e^{i ph} * rm).im
      U[m][c] = make_float2(cth * ar - sth * rn.x, cth * ai - sth * rn.y);
      U[n][c] = make_float2(sth * ar + cth * rn.x, sth * ai + cth * rn.y);
    }
    __syncthreads();
  }

  for (int idx = t; idx < DIM * 50; idx += 512) {
    int i = idx / 50, c = idx - i * 50;
    float d = dphase[i];
    float cd = cosf(d), sd = sinf(d);
    float2 u = U[i][c];
    g_U[i * DIM + c0 + c] =
        make_float2(cd * u.x - sd * u.y, cd * u.y + sd * u.x);
  }
}

// ---------------------------------------------------------------------------
// Kernel 2: pack U into f16 MFMA fragment planes (Ur, Ui, -Ui), zero-padded.
// ---------------------------------------------------------------------------
__global__ __launch_bounds__(256) void pack_kernel() {
  const int tid = threadIdx.x;
  for (int g = tid; g < 3 * 1792; g += 256) {
    int plane = g / 1792;
    int rem = g - plane * 1792;
    int lane = rem & 63;
    int tile = rem >> 6;
    int it = tile >> 2, kt = tile & 3;
    int row = it * 16 + (lane & 15);
    int col0 = kt * 32 + (lane >> 4) * 8;
    half8 h;
#pragma unroll
    for (int j = 0; j < 8; ++j) {
      int col = col0 + j;
      float v = 0.f;
      if (row < DIM && col < DIM) {
        float2 u = g_U[row * DIM + col];
        v = (plane == 0) ? u.x : ((plane == 1) ? u.y : -u.y);
      }
      h[j] = (_Float16)v;
    }
    g_frag[plane][rem] = h;
  }
}

// ---------------------------------------------------------------------------
// Kernel 3: per batch b (one block, 4 waves):
//   Tr = Ur·Xr - Ui·Xi ; Ti = Ui·Xr + Ur·Xi ; out_re = Tr·Ur^T + Ti·Ui^T
// as 16x16x32 f16 MFMAs, M=N=112 (7 tiles), K=256 (two 128-planes).
// LDS buffer S reused: phase 1 = X^T f16 [2][112][136]; phase 3 = A2 = [Tr|Ti]
// row-major [112][264]. Wave w owns M-tiles {2w, 2w+1} (tile 7 skipped).
// ---------------------------------------------------------------------------
__global__ __launch_bounds__(256) void transform_kernel(
    const float* __restrict__ xre, const float* __restrict__ xim,
    float* __restrict__ out) {
  __shared__ _Float16 S[30464];  // 60,928 B
  const int tid = threadIdx.x;
  const int wave = tid >> 6;
  const int lane = tid & 63;
  const int quad = lane >> 4;
  const int l16 = lane & 15;
  const int b = blockIdx.x;
  const float* __restrict__ Xre = xre + (size_t)b * (DIM * DIM);
  const float* __restrict__ Xim = xim + (size_t)b * (DIM * DIM);

  // ---- phase 0: zero S (X^T zero-padding relies on this) ----
  {
    int4 z = make_int4(0, 0, 0, 0);
    int4* p = (int4*)S;
    for (int i = tid; i < 30464 * 2 / 16; i += 256) p[i] = z;
  }
  __syncthreads();

  // ---- phase 1: X (fp32 [k][n]) -> X^T f16 in S: [plane][n][k], stride 136.
  // Lane holds fixed n, 4 consecutive k: 4 coalesced dword loads, 1 b64 write.
  for (int g = tid; g < 5000; g += 256) {
    int pl = g / 2500;
    int r = g - pl * 2500;
    int kq = r / 100;
    int n = r - kq * 100;
    const float* Xp = pl ? Xim : Xre;
    int k0 = kq * 4;
    half4v h;
    h[0] = (_Float16)Xp[(k0 + 0) * DIM + n];
    h[1] = (_Float16)Xp[(k0 + 1) * DIM + n];
    h[2] = (_Float16)Xp[(k0 + 2) * DIM + n];
    h[3] = (_Float16)Xp[(k0 + 3) * DIM + n];
    *(half4v*)&S[pl * 15232 + n * 136 + k0] = h;
  }
  __syncthreads();

  // ---- phase 2: stage-1 MFMAs (accumulators stay in registers) ----
  floatx4 accR[2][7], accI[2][7];
  const floatx4 zz = {0.f, 0.f, 0.f, 0.f};
#pragma unroll
  for (int a = 0; a < 2; ++a)
#pragma unroll
    for (int n = 0; n < 7; ++n) {
      accR[a][n] = zz;
      accI[a][n] = zz;
    }
  const int m0t = wave * 2;
  for (int kt = 0; kt < 8; ++kt) {
    const int ktm = kt & 3;
    const half8* frR = (kt < 4) ? g_frag[0] : g_frag[2];  // [Ur | -Ui]
    const half8* frI = (kt < 4) ? g_frag[1] : g_frag[0];  // [Ui |  Ur]
    half8 aR[2], aI[2];
#pragma unroll
    for (int mtl = 0; mtl < 2; ++mtl) {
      int mt = m0t + mtl;
      if (mt < 7) {
        int fi = (mt * 4 + ktm) * 64 + lane;
        aR[mtl] = frR[fi];
        aI[mtl] = frI[fi];
      }
    }
    const int pb = (kt >> 2) * 15232;
#pragma unroll
    for (int nt = 0; nt < 7; ++nt) {
      half8 bf =
          *(const half8*)&S[pb + (nt * 16 + l16) * 136 + ktm * 32 + quad * 8];
#pragma unroll
      for (int mtl = 0; mtl < 2; ++mtl) {
        if (m0t + mtl < 7) {
          accR[mtl][nt] = __builtin_amdgcn_mfma_f32_16x16x32_f16(
              aR[mtl], bf, accR[mtl][nt], 0, 0, 0);
          accI[mtl][nt] = __builtin_amdgcn_mfma_f32_16x16x32_f16(
              aI[mtl], bf, accI[mtl][nt], 0, 0, 0);
        }
      }
    }
  }
  __syncthreads();  // all X^T reads complete before S is overwritten

  // ---- phase 3: store T into S as A2[m][k'] (stride 264), [Tr | Ti].
  // K-pad stripes k' in [112,128) u [240,256) must be zero.
  {
    int2 z2 = make_int2(0, 0);
    for (int g = tid; g < 896; g += 256) {
      int m = g >> 3;
      int rest = g & 7;
      int base = (rest & 4) ? 240 : 112;
      int off = (rest & 3) * 4;
      *(int2*)&S[m * 264 + base + off] = z2;
    }
  }
#pragma unroll
  for (int mtl = 0; mtl < 2; ++mtl) {
    int mt = m0t + mtl;
    if (mt >= 7) continue;
    int row0 = mt * 16 + quad * 4;
#pragma unroll
    for (int nt = 0; nt < 7; ++nt) {
      int c = nt * 16 + l16;
#pragma unroll
      for (int r = 0; r < 4; ++r) {
        S[(row0 + r) * 264 + c] = (_Float16)accR[mtl][nt][r];
        S[(row0 + r) * 264 + 128 + c] = (_Float16)accI[mtl][nt][r];
      }
    }
  }
  __syncthreads();

  // ---- phase 4: stage-2 out_re = [Tr|Ti] · [Ur^T; Ui^T] ----
  floatx4 acc2[2][7];
#pragma unroll
  for (int a = 0; a < 2; ++a)
#pragma unroll
    for (int n = 0; n < 7; ++n) acc2[a][n] = zz;
  half8 a2[2][8];
#pragma unroll
  for (int mtl = 0; mtl < 2; ++mtl) {
    int mt = m0t + mtl;
    if (mt >= 7) continue;
#pragma unroll
    for (int kt2 = 0; kt2 < 8; ++kt2)
      a2[mtl][kt2] =
          *(const half8*)&S[(mt * 16 + l16) * 264 + kt2 * 32 + quad * 8];
  }
#pragma unroll
  for (int nt = 0; nt < 7; ++nt) {
#pragma unroll
    for (int kt2 = 0; kt2 < 8; ++kt2) {
      const half8* frB = (kt2 < 4) ? g_frag[0] : g_frag[1];  // [Ur^T; Ui^T]
      half8 bf = frB[(nt * 4 + (kt2 & 3)) * 64 + lane];
#pragma unroll
      for (int mtl = 0; mtl < 2; ++mtl) {
        if (m0t + mtl < 7)
          acc2[mtl][nt] = __builtin_amdgcn_mfma_f32_16x16x32_f16(
              a2[mtl][kt2], bf, acc2[mtl][nt], 0, 0, 0);
      }
    }
  }

  // ---- epilogue: real part only, guarded to 100x100 ----
  float* outb = out + (size_t)b * (DIM * DIM);
#pragma unroll
  for (int mtl = 0; mtl < 2; ++mtl) {
    int mt = m0t + mtl;
    if (mt >= 7) continue;
#pragma unroll
    for (int nt = 0; nt < 7; ++nt) {
      int c = nt * 16 + l16;
      if (c < DIM) {
#pragma unroll
        for (int r = 0; r < 4; ++r) {
          int row = mt * 16 + quad * 4 + r;
          if (row < DIM) outb[row * DIM + c] = acc2[mtl][nt][r];
        }
      }
    }
  }
}

extern "C" void kernel_launch(void* const* d_in, const int* in_sizes, int n_in,
                              void* d_out, int out_size, void* d_ws, size_t ws_size,
                              hipStream_t stream) {
  const float* xre = (const float*)d_in[0];
  const float* xim = (const float*)d_in[1];
  const float* theta = (const float*)d_in[2];
  const float* phi = (const float*)d_in[3];
  const float* dphase = (const float*)d_in[4];
  float* out = (float*)d_out;
  (void)d_ws; (void)ws_size; (void)out_size; (void)n_in;

  hipLaunchKernelGGL(build_U_kernel, dim3(2), dim3(512), 0, stream,
                     theta, phi, dphase);
  hipLaunchKernelGGL(pack_kernel, dim3(1), dim3(256), 0, stream);
  const int B = in_sizes[0] / (DIM * DIM);  // 2048
  hipLaunchKernelGGL(transform_kernel, dim3(B), dim3(256), 0, stream,
                     xre, xim, out);
}

// Round 5
// 389.216 us; speedup vs baseline: 2.5273x; 1.1575x over previous
//
#include <hip/hip_runtime.h>

#define DIM 100

typedef _Float16 half8 __attribute__((ext_vector_type(8)));
typedef _Float16 half4v __attribute__((ext_vector_type(4)));
typedef float floatx4 __attribute__((ext_vector_type(4)));

// Module-scope storage (rewritten every launch; no d_ws dependence):
__device__ float2 g_U[DIM * DIM];        // built unitary (after phase layer)
// MFMA fragment planes: [0]=Ur, [1]=Ui, [2]=-Ui. Tile (it,kt) covers U rows
// [it*16,it*16+16) x cols [kt*32,kt*32+32), zero-padded past 100.
// Element j of lane L in tile (it,kt) = plane[it*16+(L&15)][kt*32+(L>>4)*8+j].
// Serves BOTH stage-1 A-fragments and stage-2 B-fragments (identical layout).
__device__ half8 g_frag[3][7 * 4 * 64];

// ---------------------------------------------------------------------------
// Kernel 1: build U = D * T_K ... T_1 (Clements mesh scan).
// Columns evolve independently under row-pair Givens updates: 4 blocks, each
// owns 25 columns in LDS (100x25 float2 = 20 KB). All 4950 trig values are
// precomputed ONCE into per-thread registers (k = t + 512*j), staged per
// layer into a 50-entry LDS buffer -> no transcendentals inside the scan.
// ---------------------------------------------------------------------------
__global__ __launch_bounds__(512) void build_U_kernel(
    const float* __restrict__ theta, const float* __restrict__ phi,
    const float* __restrict__ dphase) {
  __shared__ float2 U[DIM][25];
  __shared__ float4 Strig[50];  // current layer: cos(th), sin(th), cos(ph), sin(ph)
  const int t = threadIdx.x;
  const int c0 = blockIdx.x * 25;

  // phase A: per-thread trig precompute (4950 pairs over 512 threads)
  float4 myTrig[10];
#pragma unroll
  for (int j = 0; j < 10; ++j) {
    int k = t + 512 * j;
    if (k < 4950) {
      float th = theta[k];
      float ph = phi[k];
      myTrig[j] = make_float4(cosf(th), sinf(th), cosf(ph), sinf(ph));
    }
  }

  for (int idx = t; idx < DIM * 25; idx += 512) {
    int i = idx / 25, c = idx - i * 25;
    U[i][c] = make_float2((i == c0 + c) ? 1.0f : 0.0f, 0.0f);
  }
  __syncthreads();

  for (int layer = 0; layer < DIM; ++layer) {
    const int start = layer & 1;
    const int npairs = 50 - start;
    const int base = (layer >> 1) * 99 + start * 50;
    // stage this layer's trig from registers into LDS
#pragma unroll
    for (int j = 0; j < 10; ++j) {
      int rel = t + 512 * j - base;
      if (rel >= 0 && rel < npairs) Strig[rel] = myTrig[j];
    }
    __syncthreads();
    for (int w = t; w < npairs * 25; w += 512) {
      const int p = w / 25;
      const int c = w - p * 25;
      const int m = start + 2 * p;
      const int n = m + 1;
      const float4 tg = Strig[p];
      const float cth = tg.x, sth = tg.y, cp = tg.z, sp = tg.w;
      const float2 rm = U[m][c];
      const float2 rn = U[n][c];
      const float ar = cp * rm.x - sp * rm.y;  // (e^{i ph} * rm).re
      const float ai = cp * rm.y + sp * rm.x;  // (e^{i ph} * rm).im
      U[m][c] = make_float2(cth * ar - sth * rn.x, cth * ai - sth * rn.y);
      U[n][c] = make_float2(sth * ar + cth * rn.x, sth * ai + cth * rn.y);
    }
    __syncthreads();
  }

  for (int idx = t; idx < DIM * 25; idx += 512) {
    int i = idx / 25, c = idx - i * 25;
    float d = dphase[i];
    float cd = cosf(d), sd = sinf(d);
    float2 u = U[i][c];
    g_U[i * DIM + c0 + c] =
        make_float2(cd * u.x - sd * u.y, cd * u.y + sd * u.x);
  }
}

// ---------------------------------------------------------------------------
// Kernel 2: pack U into f16 MFMA fragment planes (Ur, Ui, -Ui), zero-padded.
// Grid-parallel: 21 blocks x 256 threads = 5376 = 3*1792 items, one each.
// ---------------------------------------------------------------------------
__global__ __launch_bounds__(256) void pack_kernel() {
  const int g = blockIdx.x * 256 + threadIdx.x;  // < 5376 by construction
  int plane = g / 1792;
  int rem = g - plane * 1792;
  int lane = rem & 63;
  int tile = rem >> 6;
  int it = tile >> 2, kt = tile & 3;
  int row = it * 16 + (lane & 15);
  int col0 = kt * 32 + (lane >> 4) * 8;
  half8 h;
#pragma unroll
  for (int j = 0; j < 8; ++j) {
    int col = col0 + j;
    float v = 0.f;
    if (row < DIM && col < DIM) {
      float2 u = g_U[row * DIM + col];
      v = (plane == 0) ? u.x : ((plane == 1) ? u.y : -u.y);
    }
    h[j] = (_Float16)v;
  }
  g_frag[plane][rem] = h;
}

// ---------------------------------------------------------------------------
// Kernel 3: per batch b (one block, 4 waves):
//   Tr = Ur·Xr - Ui·Xi ; Ti = Ui·Xr + Ur·Xi ; out_re = Tr·Ur^T + Ti·Ui^T
// as 16x16x32 f16 MFMAs, M=N=112 (7 tiles), K=256 (two 128-planes).
// LDS buffer S reused: phase 1 = X^T f16 [2][112][136]; phase 3 = A2 = [Tr|Ti]
// row-major [112][264]. Wave w owns M-tiles {2w, 2w+1} (tile 7 skipped).
// ---------------------------------------------------------------------------
__global__ __launch_bounds__(256) void transform_kernel(
    const float* __restrict__ xre, const float* __restrict__ xim,
    float* __restrict__ out) {
  __shared__ _Float16 S[30464];  // 60,928 B
  const int tid = threadIdx.x;
  const int wave = tid >> 6;
  const int lane = tid & 63;
  const int quad = lane >> 4;
  const int l16 = lane & 15;
  const int b = blockIdx.x;
  const float* __restrict__ Xre = xre + (size_t)b * (DIM * DIM);
  const float* __restrict__ Xim = xim + (size_t)b * (DIM * DIM);

  // ---- phase 0: zero S (X^T zero-padding relies on this) ----
  {
    int4 z = make_int4(0, 0, 0, 0);
    int4* p = (int4*)S;
    for (int i = tid; i < 30464 * 2 / 16; i += 256) p[i] = z;
  }
  __syncthreads();

  // ---- phase 1: X (fp32 [k][n]) -> X^T f16 in S: [plane][n][k], stride 136.
  // Lane holds fixed n, 4 consecutive k: 4 coalesced dword loads, 1 b64 write.
  for (int g = tid; g < 5000; g += 256) {
    int pl = g / 2500;
    int r = g - pl * 2500;
    int kq = r / 100;
    int n = r - kq * 100;
    const float* Xp = pl ? Xim : Xre;
    int k0 = kq * 4;
    half4v h;
    h[0] = (_Float16)Xp[(k0 + 0) * DIM + n];
    h[1] = (_Float16)Xp[(k0 + 1) * DIM + n];
    h[2] = (_Float16)Xp[(k0 + 2) * DIM + n];
    h[3] = (_Float16)Xp[(k0 + 3) * DIM + n];
    *(half4v*)&S[pl * 15232 + n * 136 + k0] = h;
  }
  __syncthreads();

  // ---- phase 2: stage-1 MFMAs (accumulators stay in registers) ----
  floatx4 accR[2][7], accI[2][7];
  const floatx4 zz = {0.f, 0.f, 0.f, 0.f};
#pragma unroll
  for (int a = 0; a < 2; ++a)
#pragma unroll
    for (int n = 0; n < 7; ++n) {
      accR[a][n] = zz;
      accI[a][n] = zz;
    }
  const int m0t = wave * 2;
  for (int kt = 0; kt < 8; ++kt) {
    const int ktm = kt & 3;
    const half8* frR = (kt < 4) ? g_frag[0] : g_frag[2];  // [Ur | -Ui]
    const half8* frI = (kt < 4) ? g_frag[1] : g_frag[0];  // [Ui |  Ur]
    half8 aR[2], aI[2];
#pragma unroll
    for (int mtl = 0; mtl < 2; ++mtl) {
      int mt = m0t + mtl;
      if (mt < 7) {
        int fi = (mt * 4 + ktm) * 64 + lane;
        aR[mtl] = frR[fi];
        aI[mtl] = frI[fi];
      }
    }
    const int pb = (kt >> 2) * 15232;
#pragma unroll
    for (int nt = 0; nt < 7; ++nt) {
      half8 bf =
          *(const half8*)&S[pb + (nt * 16 + l16) * 136 + ktm * 32 + quad * 8];
#pragma unroll
      for (int mtl = 0; mtl < 2; ++mtl) {
        if (m0t + mtl < 7) {
          accR[mtl][nt] = __builtin_amdgcn_mfma_f32_16x16x32_f16(
              aR[mtl], bf, accR[mtl][nt], 0, 0, 0);
          accI[mtl][nt] = __builtin_amdgcn_mfma_f32_16x16x32_f16(
              aI[mtl], bf, accI[mtl][nt], 0, 0, 0);
        }
      }
    }
  }
  __syncthreads();  // all X^T reads complete before S is overwritten

  // ---- phase 3: store T into S as A2[m][k'] (stride 264), [Tr | Ti].
  // K-pad stripes k' in [112,128) u [240,256) must be zero.
  {
    int2 z2 = make_int2(0, 0);
    for (int g = tid; g < 896; g += 256) {
      int m = g >> 3;
      int rest = g & 7;
      int base = (rest & 4) ? 240 : 112;
      int off = (rest & 3) * 4;
      *(int2*)&S[m * 264 + base + off] = z2;
    }
  }
#pragma unroll
  for (int mtl = 0; mtl < 2; ++mtl) {
    int mt = m0t + mtl;
    if (mt >= 7) continue;
    int row0 = mt * 16 + quad * 4;
#pragma unroll
    for (int nt = 0; nt < 7; ++nt) {
      int c = nt * 16 + l16;
#pragma unroll
      for (int r = 0; r < 4; ++r) {
        S[(row0 + r) * 264 + c] = (_Float16)accR[mtl][nt][r];
        S[(row0 + r) * 264 + 128 + c] = (_Float16)accI[mtl][nt][r];
      }
    }
  }
  __syncthreads();

  // ---- phase 4: stage-2 out_re = [Tr|Ti] · [Ur^T; Ui^T] ----
  floatx4 acc2[2][7];
#pragma unroll
  for (int a = 0; a < 2; ++a)
#pragma unroll
    for (int n = 0; n < 7; ++n) acc2[a][n] = zz;
  half8 a2[2][8];
#pragma unroll
  for (int mtl = 0; mtl < 2; ++mtl) {
    int mt = m0t + mtl;
    if (mt >= 7) continue;
#pragma unroll
    for (int kt2 = 0; kt2 < 8; ++kt2)
      a2[mtl][kt2] =
          *(const half8*)&S[(mt * 16 + l16) * 264 + kt2 * 32 + quad * 8];
  }
#pragma unroll
  for (int nt = 0; nt < 7; ++nt) {
#pragma unroll
    for (int kt2 = 0; kt2 < 8; ++kt2) {
      const half8* frB = (kt2 < 4) ? g_frag[0] : g_frag[1];  // [Ur^T; Ui^T]
      half8 bf = frB[(nt * 4 + (kt2 & 3)) * 64 + lane];
#pragma unroll
      for (int mtl = 0; mtl < 2; ++mtl) {
        if (m0t + mtl < 7)
          acc2[mtl][nt] = __builtin_amdgcn_mfma_f32_16x16x32_f16(
              a2[mtl][kt2], bf, acc2[mtl][nt], 0, 0, 0);
      }
    }
  }

  // ---- epilogue: real part only, guarded to 100x100 ----
  float* outb = out + (size_t)b * (DIM * DIM);
#pragma unroll
  for (int mtl = 0; mtl < 2; ++mtl) {
    int mt = m0t + mtl;
    if (mt >= 7) continue;
#pragma unroll
    for (int nt = 0; nt < 7; ++nt) {
      int c = nt * 16 + l16;
      if (c < DIM) {
#pragma unroll
        for (int r = 0; r < 4; ++r) {
          int row = mt * 16 + quad * 4 + r;
          if (row < DIM) outb[row * DIM + c] = acc2[mtl][nt][r];
        }
      }
    }
  }
}

extern "C" void kernel_launch(void* const* d_in, const int* in_sizes, int n_in,
                              void* d_out, int out_size, void* d_ws, size_t ws_size,
                              hipStream_t stream) {
  const float* xre = (const float*)d_in[0];
  const float* xim = (const float*)d_in[1];
  const float* theta = (const float*)d_in[2];
  const float* phi = (const float*)d_in[3];
  const float* dphase = (const float*)d_in[4];
  float* out = (float*)d_out;
  (void)d_ws; (void)ws_size; (void)out_size; (void)n_in;

  hipLaunchKernelGGL(build_U_kernel, dim3(4), dim3(512), 0, stream,
                     theta, phi, dphase);
  hipLaunchKernelGGL(pack_kernel, dim3(21), dim3(256), 0, stream);
  const int B = in_sizes[0] / (DIM * DIM);  // 2048
  hipLaunchKernelGGL(transform_kernel, dim3(B), dim3(256), 0, stream,
                     xre, xim, out);
}